// Round 1
// baseline (53.974 us; speedup 1.0000x reference)
//
#include <hip/hip_runtime.h>
#include <math.h>

// SineGenVITS: B=16, L=131072, DIM=9 (fund + 8 harmonics)
// out = [sine_waves (B,L,9) | uv (B,L,1) | noise (B,L,9)], float32.
//
// Key identity: sin(2*pi*cumsum(rad+shift)) depends only on phase mod 1,
// and the reference's integer wrap-shifts vanish mod 1, so
//   phase[b,t,d] = frac( k_d * C_t / SR + rand_ini[b,d] ),  C_t = sum f0[b,0..t]
// computed exactly in f64 matches the reference within ~1e-3 (threshold 2e-2).

#define Bq 16
#define Lq 131072
#define DIMq 9
#define CHUNK 2048
#define NCHUNK (Lq / CHUNK)          // 64 chunks per batch row
#define NTHREADS 256
#define PER_THREAD (CHUNK / NTHREADS) // 8

static __device__ __forceinline__ int pad9(int p) { return p + (p >> 3); }

// Pass 1: per-(b,chunk) f64 partial sums of f0.
__global__ void __launch_bounds__(NTHREADS) k_partials(
    const float* __restrict__ f0, double* __restrict__ part) {
  int b = blockIdx.x / NCHUNK, c = blockIdx.x % NCHUNK;
  const float* p = f0 + (size_t)b * Lq + (size_t)c * CHUNK;
  double s = 0.0;
#pragma unroll
  for (int j = 0; j < PER_THREAD; ++j) s += (double)p[j * NTHREADS + threadIdx.x];
  __shared__ double sd[NTHREADS];
  sd[threadIdx.x] = s;
  __syncthreads();
  for (int off = NTHREADS / 2; off > 0; off >>= 1) {
    if (threadIdx.x < off) sd[threadIdx.x] += sd[threadIdx.x + off];
    __syncthreads();
  }
  if (threadIdx.x == 0) part[blockIdx.x] = sd[0];
}

// Pass 2: exclusive scan of NCHUNK partials per batch row (tiny).
__global__ void k_scan(double* __restrict__ part) {
  if (threadIdx.x == 0) {
    double run = 0.0;
    double* p = part + (size_t)blockIdx.x * NCHUNK;
    for (int c = 0; c < NCHUNK; ++c) { double v = p[c]; p[c] = run; run += v; }
  }
}

// Pass 3: fused block scan + output generation.
__global__ void __launch_bounds__(NTHREADS) k_main(
    const float* __restrict__ f0, const float* __restrict__ rini,
    const float* __restrict__ nz, const double* __restrict__ pref,
    float* __restrict__ out0, float* __restrict__ out1, float* __restrict__ out2) {
  int b = blockIdx.x / NCHUNK, c = blockIdx.x % NCHUNK;
  int tid = threadIdx.x;
  size_t rowbase = (size_t)b * Lq + (size_t)c * CHUNK;

  __shared__ float f0s[CHUNK + CHUNK / 8];   // padded stride-9 to break conflicts
  __shared__ double Cl[CHUNK + CHUNK / 8];
  __shared__ double sd[NTHREADS];

  // Coalesced load of f0 chunk into LDS (transposed access later).
#pragma unroll
  for (int j = 0; j < PER_THREAD; ++j) {
    int p = j * NTHREADS + tid;
    f0s[pad9(p)] = f0[rowbase + p];
  }
  __syncthreads();

  // Thread-local inclusive sums over contiguous 8 timesteps.
  double run = 0.0;
  double inc[PER_THREAD];
#pragma unroll
  for (int j = 0; j < PER_THREAD; ++j) {
    run += (double)f0s[pad9(tid * PER_THREAD + j)];
    inc[j] = run;
  }
  sd[tid] = run;
  __syncthreads();
  // Hillis-Steele inclusive scan over 256 thread totals.
#pragma unroll
  for (int off = 1; off < NTHREADS; off <<= 1) {
    double v = (tid >= off) ? sd[tid - off] : 0.0;
    __syncthreads();
    sd[tid] += v;
    __syncthreads();
  }
  double base = pref[blockIdx.x] + (sd[tid] - run);  // exclusive prefix
#pragma unroll
  for (int j = 0; j < PER_THREAD; ++j)
    Cl[pad9(tid * PER_THREAD + j)] = base + inc[j];
  __syncthreads();

  float ini[DIMq];
#pragma unroll
  for (int d = 0; d < DIMq; ++d) ini[d] = rini[b * DIMq + d];

  const double invsr = 1.0 / 22050.0;
  const float nampU = (float)(0.1 / 3.0);  // matches f32(double 0.1/3)

  // Elementwise phase: lane-consecutive t for coalesced global access.
  for (int j = 0; j < PER_THREAD; ++j) {
    int p = j * NTHREADS + tid;
    size_t t = rowbase + p;
    float f = f0s[pad9(p)];
    bool v = f > 0.0f;
    out1[t] = v ? 1.0f : 0.0f;
    double x = Cl[pad9(p)] * invsr;
    float namp = v ? 0.003f : nampU;
    const float* nzp = nz + t * DIMq;
    float* o0 = out0 + t * DIMq;
    float* o2 = out2 + t * DIMq;
#pragma unroll
    for (int d = 0; d < DIMq; ++d) {
      float nzv = nzp[d];
      float noise = namp * nzv;
      double ph = x * (double)(d + 1) + (double)ini[d];
      ph -= floor(ph);  // frac in [0,1) revolutions
      float s = __builtin_amdgcn_sinf((float)ph) * 0.1f;  // v_sin: sin(2*pi*x)
      o2[d] = noise;
      o0[d] = v ? (s + noise) : noise;
    }
  }
}

extern "C" void kernel_launch(void* const* d_in, const int* in_sizes, int n_in,
                              void* d_out, int out_size, void* d_ws, size_t ws_size,
                              hipStream_t stream) {
  const float* f0 = (const float*)d_in[0];    // (B, L, 1)
  const float* rini = (const float*)d_in[1];  // (B, DIM)
  const float* nz = (const float*)d_in[2];    // (B, L, DIM)
  float* out = (float*)d_out;
  float* out0 = out;                                  // sine_waves (B,L,9)
  float* out1 = out + (size_t)Bq * Lq * DIMq;         // uv (B,L,1)
  float* out2 = out1 + (size_t)Bq * Lq;               // noise (B,L,9)
  double* part = (double*)d_ws;                       // B*NCHUNK doubles = 8 KB

  k_partials<<<Bq * NCHUNK, NTHREADS, 0, stream>>>(f0, part);
  k_scan<<<Bq, 64, 0, stream>>>(part);
  k_main<<<Bq * NCHUNK, NTHREADS, 0, stream>>>(f0, rini, nz, part,
                                               out0, out1, out2);
}

// Round 2
// 47.971 us; speedup vs baseline: 1.1251x; 1.1251x over previous
//
#include <hip/hip_runtime.h>
#include <math.h>

// SineGenVITS: B=16, L=131072, DIM=9. out = [sine (B,L,9) | uv (B,L,1) | noise (B,L,9)] f32.
//
// phase[b,t,d] = frac( k_d * C_t / SR + rand_ini[b,d] ),  C_t = sum f0[b,0..t] (f64 exact).
// The reference's integer wrap-shifts vanish mod 1; its own f32 error >> ours.
//
// 2 kernels: (1) per-chunk f64 partial sums of f0; (2) fused: block scan
// (thread-serial 8 + wave shfl scan + cross-wave via LDS + global-partial
// prefix via lane<c shfl reduce), then flat-float4 elementwise generation.

#define Bq 16
#define Lq 131072
#define DIMq 9
#define CHUNK 2048
#define NCHUNK (Lq / CHUNK)  // 64
#define NT 256
#define PT 8                 // timesteps per thread
#define Q4 (CHUNK * DIMq / 4 / NT)  // 18 float4s per thread in phase 2

__global__ void __launch_bounds__(NT) k_partials(const float* __restrict__ f0,
                                                 double* __restrict__ part) {
  int b = blockIdx.x >> 6, tid = threadIdx.x, lane = tid & 63, wave = tid >> 6;
  const float* p = f0 + (size_t)b * Lq + (size_t)(blockIdx.x & 63) * CHUNK + tid * PT;
  float4 x = *(const float4*)p;
  float4 y = *(const float4*)(p + 4);
  double s = ((double)x.x + (double)x.y) + ((double)x.z + (double)x.w) +
             ((double)y.x + (double)y.y) + ((double)y.z + (double)y.w);
#pragma unroll
  for (int d = 32; d > 0; d >>= 1) s += __shfl_xor(s, d, 64);
  __shared__ double ws[NT / 64];
  if (lane == 0) ws[wave] = s;
  __syncthreads();
  if (tid == 0) part[blockIdx.x] = ws[0] + ws[1] + ws[2] + ws[3];
}

__global__ void __launch_bounds__(NT) k_main(
    const float* __restrict__ f0, const float* __restrict__ rini,
    const float* __restrict__ nz, const double* __restrict__ part,
    float* __restrict__ out0, float* __restrict__ out1,
    float* __restrict__ out2) {
  int bc = blockIdx.x;
  int b = bc >> 6, c = bc & 63;
  int tid = threadIdx.x, lane = tid & 63, wave = tid >> 6;
  size_t t0g = (size_t)b * Lq + (size_t)c * CHUNK;

  __shared__ float p1s[CHUNK + CHUNK / 8];   // frac(C_t/SR), pad-8: idx t+(t>>3)
  __shared__ float nmps[CHUNK + CHUNK / 8];  // +0.003 voiced / -(0.1/3) unvoiced
  __shared__ float inis[DIMq];
  __shared__ double wsum[NT / 64];

  // ---- phase 1: scan ----
  const float* fp = f0 + t0g + tid * PT;
  float4 fa = *(const float4*)fp;
  float4 fb = *(const float4*)(fp + 4);
  float fv[PT] = {fa.x, fa.y, fa.z, fa.w, fb.x, fb.y, fb.z, fb.w};
  double run = 0.0, inc[PT];
#pragma unroll
  for (int j = 0; j < PT; ++j) { run += (double)fv[j]; inc[j] = run; }
  double tot = run;  // wave-inclusive scan of thread totals
#pragma unroll
  for (int d = 1; d < 64; d <<= 1) {
    double o = __shfl_up(tot, d, 64);
    if (lane >= d) tot += o;
  }
  if (lane == 63) wsum[wave] = tot;
  if (tid < DIMq) inis[tid] = rini[b * DIMq + tid];
  __syncthreads();
  // block prefix = sum of this row's chunk partials before c (redundant per wave)
  double pv = (lane < c) ? part[(b << 6) + lane] : 0.0;
#pragma unroll
  for (int d = 32; d > 0; d >>= 1) pv += __shfl_xor(pv, d, 64);
  double wpre = 0.0;
  for (int w = 0; w < wave; ++w) wpre += wsum[w];
  double base = pv + wpre + (tot - run);  // exclusive prefix for this thread
  const double invsr = 1.0 / 22050.0;
  const float nampU = (float)(0.1 / 3.0);
  float uvv[PT];
#pragma unroll
  for (int j = 0; j < PT; ++j) {
    double ph = (base + inc[j]) * invsr;
    ph -= floor(ph);
    int t = tid * PT + j;
    p1s[t + (t >> 3)] = (float)ph;
    bool v = fv[j] > 0.0f;
    nmps[t + (t >> 3)] = v ? 0.003f : -nampU;
    uvv[j] = v ? 1.0f : 0.0f;
  }
  *(float4*)(out1 + t0g + tid * PT) = make_float4(uvv[0], uvv[1], uvv[2], uvv[3]);
  *(float4*)(out1 + t0g + tid * PT + 4) = make_float4(uvv[4], uvv[5], uvv[6], uvv[7]);
  __syncthreads();

  // ---- phase 2: flat float4 elementwise over chunk*9 elements ----
  const float4* nzc = (const float4*)(nz + t0g * DIMq);
  float4* o0c = (float4*)(out0 + t0g * DIMq);
  float4* o2c = (float4*)(out2 + t0g * DIMq);

  auto gen = [&](int t, int d, float nzv, float& r0, float& r2) {
    int ti = t + (t >> 3);
    float p1 = p1s[ti], nm = nmps[ti];
    float ph = (float)(d + 1) * p1 + inis[d];
    ph -= floorf(ph);
    float s = __builtin_amdgcn_sinf(ph) * 0.1f;
    float noise = fabsf(nm) * nzv;
    r2 = noise;
    r0 = (nm > 0.0f) ? s + noise : noise;
  };

#pragma unroll 6
  for (int w = 0; w < Q4; ++w) {
    int q = w * NT + tid;
    int e = q * 4;
    int t = (int)(((unsigned)e * 7282u) >> 16);  // e/9, exact for e<18432
    int d = e - t * 9;
    float4 nzv = nzc[q];
    float4 r0, r2;
    gen(t, d, nzv.x, r0.x, r2.x); if (++d == 9) { d = 0; ++t; }
    gen(t, d, nzv.y, r0.y, r2.y); if (++d == 9) { d = 0; ++t; }
    gen(t, d, nzv.z, r0.z, r2.z); if (++d == 9) { d = 0; ++t; }
    gen(t, d, nzv.w, r0.w, r2.w);
    o0c[q] = r0;
    o2c[q] = r2;
  }
}

extern "C" void kernel_launch(void* const* d_in, const int* in_sizes, int n_in,
                              void* d_out, int out_size, void* d_ws, size_t ws_size,
                              hipStream_t stream) {
  const float* f0 = (const float*)d_in[0];
  const float* rini = (const float*)d_in[1];
  const float* nz = (const float*)d_in[2];
  float* out = (float*)d_out;
  float* out0 = out;                           // sine_waves (B,L,9)
  float* out1 = out + (size_t)Bq * Lq * DIMq;  // uv (B,L,1)
  float* out2 = out1 + (size_t)Bq * Lq;        // noise (B,L,9)
  double* part = (double*)d_ws;                // B*NCHUNK doubles = 8 KB

  k_partials<<<Bq * NCHUNK, NT, 0, stream>>>(f0, part);
  k_main<<<Bq * NCHUNK, NT, 0, stream>>>(f0, rini, nz, part, out0, out1, out2);
}